// Round 12
// baseline (99.060 us; speedup 1.0000x reference)
//
#include <hip/hip_runtime.h>
#include <math.h>

#define DM    1024
#define DQK   128
#define BATCH 4
#define SEQ   4096
// 1/sqrt(128) * log2(e) folded into Wq/bq at wcvt time -> softmax uses exp2 directly
#define QSCALE (0.08838834764831845f * 1.4426950408889634f)
#define DEFER_THR 6.0f

typedef _Float16 f16;
typedef _Float16 f16x4 __attribute__((ext_vector_type(4)));
typedef _Float16 f16x8 __attribute__((ext_vector_type(8)));
typedef float    f32x4 __attribute__((ext_vector_type(4)));

__device__ __forceinline__ void stage16(const void* g, unsigned char* l) {
    __builtin_amdgcn_global_load_lds(
        (const __attribute__((address_space(1))) unsigned int*)g,
        (__attribute__((address_space(3))) unsigned int*)l, 16, 0, 0);
}

// ---------------- W convert/transpose pre-kernel (unchanged) ----------------
__global__ __launch_bounds__(256) void wcvt_kernel(
    const float* __restrict__ Wq, const float* __restrict__ bq,
    const float* __restrict__ Wk, const float* __restrict__ bk,
    const float* __restrict__ Wv, const float* __restrict__ bv,
    f16* __restrict__ wt, float* __restrict__ biasf)
{
    const int sel = blockIdx.x >> 3;
    const int k0  = (blockIdx.x & 7) * 128;
    const float* W; const float* b; float sc;
    if (sel == 0)      { W = Wq; b = bq; sc = QSCALE; }
    else if (sel == 1) { W = Wk; b = bk; sc = 1.0f; }
    else               { W = Wv; b = bv; sc = 1.0f; }

    __shared__ f16 tile[128][136];

    #pragma unroll
    for (int it = 0; it < 16; ++it) {
        int flat = threadIdx.x + it * 256;
        int kk   = flat >> 5;
        int c4   = flat & 31;
        float4 w4 = *(const float4*)(W + (size_t)(k0 + kk) * DQK + c4 * 4);
        tile[kk][c4 * 4 + 0] = (f16)(w4.x * sc);
        tile[kk][c4 * 4 + 1] = (f16)(w4.y * sc);
        tile[kk][c4 * 4 + 2] = (f16)(w4.z * sc);
        tile[kk][c4 * 4 + 3] = (f16)(w4.w * sc);
    }
    __syncthreads();

    #pragma unroll
    for (int it = 0; it < 8; ++it) {
        int flat = threadIdx.x + it * 256;
        int n    = flat >> 4;
        int kc   = flat & 15;
        f16x8 v;
        #pragma unroll
        for (int i = 0; i < 8; ++i) v[i] = tile[kc * 8 + i][n];
        *(f16x8*)(wt + (size_t)(sel * 128 + n) * DM + k0 + kc * 8) = v;
    }
    if ((blockIdx.x & 7) == 0 && threadIdx.x < 128)
        biasf[sel * 128 + threadIdx.x] = b[threadIdx.x] * sc;
}

// ---------------- Fused QKV projection: BK=32, 2 blocks/CU ----------------
// 256 blocks x 512 thr, 2 blocks/CU (59 KB LDS). Block: 64 rows x 384 cols; wave w:
// 64 rows x 48 cols. Per iter t (k-chunk of 32): x [64][40-pad] f16 reg-staged dbuf
// (stride 80 B = conflict-free b128 column reads); W slice [384][32] f16 (24 KB) via
// global_load_lds dbuf, XOR swizzle chunk^=(n>>1)&3 through pre-swizzled source.
#define PXOFF 0u        // 2 x 5120 B x buffers
#define PWOFF 10240u    // 2 x 24576 B W buffers

__global__ __launch_bounds__(512, 4) void proj_kernel(
    const float* __restrict__ x, const f16* __restrict__ wt,
    const float* __restrict__ biasf,
    f16* __restrict__ qo, f16* __restrict__ ko, f16* __restrict__ vto)
{
    __shared__ __align__(16) unsigned char smem[59392];

    const int tid  = threadIdx.x;
    const int lane = tid & 63;
    const int w    = tid >> 6;
    const int c    = lane & 15;
    const int g    = lane >> 4;
    const int r0   = blockIdx.x * 64;

    // x staging role: thread -> (row, 4-f16 group)
    const int srow = tid >> 3;                 // 0..63
    const int sk4  = tid & 7;                  // 0..7
    const float* const xsrc  = x + (size_t)(r0 + srow) * DM + sk4 * 4;
    const unsigned     xwoff = (unsigned)(srow * 80 + sk4 * 8);

    // W staging role: lane -> (n within 128-group, chunk)
    const char* const wtB  = (const char*)wt;
    const int         wn_l = w * 16 + (lane >> 2);   // + cc*128
    const int         wcl  = lane & 3;

    f32x4 acc[4][3];
    #pragma unroll
    for (int rf = 0; rf < 4; ++rf)
        #pragma unroll
        for (int nf = 0; nf < 3; ++nf) acc[rf][nf] = (f32x4)0.f;

    float4 xa;
    auto gload = [&](int t) { xa = *(const float4*)(xsrc + t * 32); };
    auto swrite = [&](int buf) {
        f16x4 h;
        h[0] = (f16)xa.x; h[1] = (f16)xa.y; h[2] = (f16)xa.z; h[3] = (f16)xa.w;
        *(f16x4*)(smem + PXOFF + (unsigned)buf * 5120u + xwoff) = h;
    };
    auto stage_W = [&](int t, int pbuf) {
        unsigned char* wdst = smem + PWOFF + (unsigned)pbuf * 24576u + (unsigned)w * 1024u;
        #pragma unroll
        for (int cc = 0; cc < 3; ++cc) {
            const int n = wn_l + cc * 128;     // 0..383
            stage16(wtB + (size_t)n * 2048 + (size_t)t * 64
                        + (unsigned)((wcl ^ ((n >> 1) & 3)) * 16),
                    wdst + cc * 8192);
        }
    };

    gload(0); swrite(0);
    gload(1);
    stage_W(0, 0);
    __syncthreads();   // x(0) visible, W(0) drained

    for (int t = 0; t < 32; ++t) {
        const int cur = t & 1;
        if (t < 31) swrite(cur ^ 1);          // x(t+1), loaded last iter
        if (t < 30) gload(t + 2);             // x prefetch 2 ahead
        if (t < 31) stage_W(t + 1, cur ^ 1);  // W(t+1), drains at end-of-iter barrier

        // A-frags from padded x LDS: row = rf*16+c, k = g*8..g*8+7
        f16x8 af[4];
        #pragma unroll
        for (int rf = 0; rf < 4; ++rf)
            af[rf] = *(const f16x8*)(smem + PXOFF + (unsigned)cur * 5120u
                + (unsigned)((rf * 16 + c) * 80 + g * 16));

        // B-frags from swizzled W LDS: n = w*48 + nf*16 + c, chunk = g ^ ((n>>1)&3)
        unsigned char* const wbase = smem + PWOFF + (unsigned)cur * 24576u;
        #pragma unroll
        for (int nf = 0; nf < 3; ++nf) {
            const int n = w * 48 + nf * 16 + c;
            f16x8 bf = *(const f16x8*)(wbase
                + (unsigned)(n * 64 + ((g ^ ((n >> 1) & 3)) * 16)));
            #pragma unroll
            for (int rf = 0; rf < 4; ++rf)
                acc[rf][nf] = __builtin_amdgcn_mfma_f32_16x16x32_f16(
                    af[rf], bf, acc[rf][nf], 0, 0, 0);
        }
        __syncthreads();
    }

    // ---- epilogue: bias + f16, bounce through LDS tile [64][392] for coalesced stores ----
    f16* const tile = (f16*)smem;
    #pragma unroll
    for (int rf = 0; rf < 4; ++rf)
        #pragma unroll
        for (int nf = 0; nf < 3; ++nf) {
            const int n  = w * 48 + nf * 16 + c;
            const float bb = biasf[n];
            #pragma unroll
            for (int r = 0; r < 4; ++r) {
                const int row = rf * 16 + 4 * g + r;
                tile[row * 392 + n] = (f16)(acc[rf][nf][r] + bb);
            }
        }
    __syncthreads();

    #pragma unroll
    for (int it = 0; it < 2; ++it) {
        const int u   = tid + it * 512;
        const int row = u >> 4;
        const int c8  = (u & 15) * 8;
        *(f16x8*)(qo + (size_t)(r0 + row) * DQK + c8) = *(const f16x8*)&tile[row * 392 + c8];
        *(f16x8*)(ko + (size_t)(r0 + row) * DQK + c8) = *(const f16x8*)&tile[row * 392 + 128 + c8];
    }
    const int gb = r0 >> 12;
    const int s0 = r0 & (SEQ - 1);
    #pragma unroll
    for (int it = 0; it < 2; ++it) {
        const int u  = tid + it * 512;
        const int d  = u >> 3;
        const int s8 = (u & 7) * 8;
        f16x8 vv;
        #pragma unroll
        for (int i = 0; i < 8; ++i) vv[i] = tile[(s8 + i) * 392 + 256 + d];
        *(f16x8*)(vto + ((size_t)gb * DQK + d) * SEQ + s0 + s8) = vv;
    }
}

// ---------------- Flash attention: EXACT round-4 winner (66 us) ----------------
#define KOFF 0u
#define VOFF 65536u
#define POFF 131072u
#define MOFF 151552u
#define LOFF 152576u

__global__ __launch_bounds__(512, 2) void attn_kernel(
    const f16* __restrict__ qg, const f16* __restrict__ kg,
    const f16* __restrict__ vtg, float* __restrict__ out)
{
    __shared__ __align__(16) unsigned char smem[153600];

    const int tid  = threadIdx.x;
    const int lane = tid & 63;
    const int w    = tid >> 6;      // 0..7
    const int wq   = w >> 2;        // 0..1
    const int wk   = w & 3;         // 0..3
    const int c    = lane & 15;
    const int g    = lane >> 4;     // 0..3

    const int bid = blockIdx.x;
    const int xcd = bid & 7;
    const int bb  = xcd >> 1;
    const int qt  = (bid >> 3) | ((xcd & 1) << 5);
    const int q0  = qt * 64;

    const f16*  qb = qg  + (size_t)bb * SEQ * DQK;
    const char* kB = (const char*)(kg  + (size_t)bb * SEQ * DQK);
    const char* vB = (const char*)(vtg + (size_t)bb * DQK * SEQ);

    // Q frags (B-operand for swapped QK^T): q = 16n + c, k(d) = ks*32 + 8g + i
    f16x8 qf[2][4];
    {
        const f16* qr = qb + (size_t)(q0 + wq * 32) * DQK;
        #pragma unroll
        for (int n = 0; n < 2; ++n)
            #pragma unroll
            for (int ks = 0; ks < 4; ++ks)
                qf[n][ks] = *(const f16x8*)(qr + (n * 16 + c) * DQK + ks * 32 + 8 * g);
    }

    f32x4 o[2][9];   // [n (q-frag)][d-frag 0..7, 8 = ones column = running l]
    #pragma unroll
    for (int n = 0; n < 2; ++n)
        #pragma unroll
        for (int f = 0; f < 9; ++f) o[n][f] = (f32x4)0.f;
    float m_run[2] = {-3e38f, -3e38f};   // S^T domain: q = 16n + c

    f16x8 onesf;
    #pragma unroll
    for (int i = 0; i < 8; ++i) onesf[i] = (f16)1.0f;

    const unsigned wbase = (unsigned)(tid >> 6) * 1024;

    auto stage_tiles = [&](int t, int pbuf) {
        const int kv0 = t * 128;
        unsigned char* kdst = smem + KOFF + (unsigned)pbuf * 32768u + wbase;
        unsigned char* vdst = smem + VOFF + (unsigned)pbuf * 32768u + wbase;
        #pragma unroll
        for (int cc = 0; cc < 4; ++cc) {
            const int j   = tid + cc * 512;
            const int row = j >> 4;
            const int col = j & 15;
            const int sw  = (col ^ (row & 7)) * 16;
            stage16(kB + (size_t)(kv0 + row) * 256 + sw, kdst + cc * 8192);
            stage16(vB + (size_t)row * 8192 + (size_t)kv0 * 2 + sw, vdst + cc * 8192);
        }
    };

    stage_tiles(0, 0);
    __syncthreads();

    unsigned char* const pmine = smem + POFF + (unsigned)w * 2560u;

    for (int t = 0; t < 32; ++t) {
        const int pb = t & 1;
        if (t < 31) stage_tiles(t + 1, pb ^ 1);

        unsigned char* const kbase = smem + KOFF + (unsigned)pb * 32768u;
        unsigned char* const vbase = smem + VOFF + (unsigned)pb * 32768u;

        // ---- swapped QK^T: S^T[kv 32][q 32] per wave ----
        f32x4 s[2][2];   // [m (kv16)][n (q16)]
        s[0][0] = (f32x4)0.f; s[0][1] = (f32x4)0.f;
        s[1][0] = (f32x4)0.f; s[1][1] = (f32x4)0.f;
        __builtin_amdgcn_s_setprio(1);
        #pragma unroll
        for (int ks = 0; ks < 4; ++ks) {
            #pragma unroll
            for (int m = 0; m < 2; ++m) {
                f16x8 kf = *(const f16x8*)(kbase
                    + (unsigned)(wk * 32 + m * 16 + c) * 256u
                    + (unsigned)(((4 * ks + g) ^ (c & 7)) * 16));
                s[m][0] = __builtin_amdgcn_mfma_f32_16x16x32_f16(kf, qf[0][ks], s[m][0], 0, 0, 0);
                s[m][1] = __builtin_amdgcn_mfma_f32_16x16x32_f16(kf, qf[1][ks], s[m][1], 0, 0, 0);
            }
        }
        __builtin_amdgcn_s_setprio(0);

        // ---- lane-local softmax max (per q-row = 16n + c) ----
        float mt[2];
        #pragma unroll
        for (int n = 0; n < 2; ++n) {
            float a0 = fmaxf(fmaxf(s[0][n][0], s[0][n][1]), fmaxf(s[0][n][2], s[0][n][3]));
            float a1 = fmaxf(fmaxf(s[1][n][0], s[1][n][1]), fmaxf(s[1][n][2], s[1][n][3]));
            float v  = fmaxf(a0, a1);
            v = fmaxf(v, __shfl_xor(v, 16, 64));
            v = fmaxf(v, __shfl_xor(v, 32, 64));
            mt[n] = v;
        }

        // ---- defer-max: rescale only when the running max grows past THR ----
        bool need = (mt[0] > m_run[0] + DEFER_THR) || (mt[1] > m_run[1] + DEFER_THR);
        if (__any(need)) {
            float al[2];
            #pragma unroll
            for (int n = 0; n < 2; ++n) {
                float mn = fmaxf(m_run[n], mt[n]);
                al[n] = __builtin_amdgcn_exp2f(m_run[n] - mn);
                m_run[n] = mn;
            }
            float alo[2][4];
            #pragma unroll
            for (int n = 0; n < 2; ++n)
                #pragma unroll
                for (int r = 0; r < 4; ++r)
                    alo[n][r] = __shfl(al[n], 4 * g + r, 16);
            #pragma unroll
            for (int n = 0; n < 2; ++n)
                #pragma unroll
                for (int f = 0; f < 9; ++f)
                    #pragma unroll
                    for (int r = 0; r < 4; ++r) o[n][f][r] *= alo[n][r];
        }

        // ---- P = exp2(S^T - m), packed b64 stores: P[q = 16n+c][kv = 16m+4g .. +3] ----
        #pragma unroll
        for (int n = 0; n < 2; ++n)
            #pragma unroll
            for (int m = 0; m < 2; ++m) {
                f16x4 h;
                #pragma unroll
                for (int r = 0; r < 4; ++r)
                    h[r] = (f16)__builtin_amdgcn_exp2f(s[m][n][r] - m_run[n]);
                *(f16x4*)(pmine + (unsigned)(16 * n + c) * 80u + (unsigned)(32 * m + 8 * g)) = h;
            }

        // ---- PV: O[32 q][128 d] += P[32 q][32 kv] * V[32 kv][128 d] ----
        f16x8 pa[2];
        pa[0] = *(const f16x8*)(pmine + (unsigned)(c) * 80u + 16u * g);
        pa[1] = *(const f16x8*)(pmine + (unsigned)(16 + c) * 80u + 16u * g);
        __builtin_amdgcn_s_setprio(1);
        #pragma unroll
        for (int df = 0; df < 8; ++df) {
            f16x8 vf = *(const f16x8*)(vbase
                + (unsigned)(df * 16 + c) * 256u
                + (unsigned)(((4 * wk + g) ^ (c & 7)) * 16));
            o[0][df] = __builtin_amdgcn_mfma_f32_16x16x32_f16(pa[0], vf, o[0][df], 0, 0, 0);
            o[1][df] = __builtin_amdgcn_mfma_f32_16x16x32_f16(pa[1], vf, o[1][df], 0, 0, 0);
        }
        o[0][8] = __builtin_amdgcn_mfma_f32_16x16x32_f16(pa[0], onesf, o[0][8], 0, 0, 0);
        o[1][8] = __builtin_amdgcn_mfma_f32_16x16x32_f16(pa[1], onesf, o[1][8], 0, 0, 0);
        __builtin_amdgcn_s_setprio(0);

        __syncthreads();
    }

    // ship final m to O domain (q = 16n + 4g + r)
    float m_o[2][4];
    #pragma unroll
    for (int n = 0; n < 2; ++n)
        #pragma unroll
        for (int r = 0; r < 4; ++r)
            m_o[n][r] = __shfl(m_run[n], 4 * g + r, 16);

    // ---- merge the 4 kv-splits (per wq) via LDS ----
    float* const mld  = (float*)(smem + MOFF);
    float* const lld  = (float*)(smem + LOFF);
    float* const olds = (float*)smem;

    if (wk > 0) {
        const int base = (wq * 3 + (wk - 1)) * 32;
        #pragma unroll
        for (int n = 0; n < 2; ++n)
            #pragma unroll
            for (int f = 0; f < 8; ++f)
                #pragma unroll
                for (int r = 0; r < 4; ++r)
                    olds[(size_t)(base + n * 16 + 4 * g + r) * 132 + f * 16 + c] = o[n][f][r];
        if (c == 0) {
            #pragma unroll
            for (int n = 0; n < 2; ++n)
                #pragma unroll
                for (int r = 0; r < 4; ++r) {
                    mld[(wq * 4 + wk) * 32 + n * 16 + 4 * g + r] = m_o[n][r];
                    lld[(wq * 4 + wk) * 32 + n * 16 + 4 * g + r] = o[n][8][r];
                }
        }
    }
    __syncthreads();

    if (wk == 0) {
        #pragma unroll
        for (int n = 0; n < 2; ++n) {
            #pragma unroll
            for (int r = 0; r < 4; ++r) {
                const int rl = n * 16 + 4 * g + r;
                const float m0 = m_o[n][r];
                const float m1 = mld[(wq * 4 + 1) * 32 + rl];
                const float m2 = mld[(wq * 4 + 2) * 32 + rl];
                const float m3 = mld[(wq * 4 + 3) * 32 + rl];
                const float ms = fmaxf(fmaxf(m0, m1), fmaxf(m2, m3));
                const float a0 = __builtin_amdgcn_exp2f(m0 - ms);
                const float a1 = __builtin_amdgcn_exp2f(m1 - ms);
                const float a2 = __builtin_amdgcn_exp2f(m2 - ms);
                const float a3 = __builtin_amdgcn_exp2f(m3 - ms);
                const float ls = a0 * o[n][8][r]
                               + a1 * lld[(wq * 4 + 1) * 32 + rl]
                               + a2 * lld[(wq * 4 + 2) * 32 + rl]
                               + a3 * lld[(wq * 4 + 3) * 32 + rl];
                const float inv = 1.0f / ls;
                float* orow = out + ((size_t)bb * SEQ + q0 + wq * 32 + rl) * DQK;
                #pragma unroll
                for (int f = 0; f < 8; ++f) {
                    float v = a0 * o[n][f][r]
                            + a1 * olds[(size_t)((wq * 3 + 0) * 32 + rl) * 132 + f * 16 + c]
                            + a2 * olds[(size_t)((wq * 3 + 1) * 32 + rl) * 132 + f * 16 + c]
                            + a3 * olds[(size_t)((wq * 3 + 2) * 32 + rl) * 132 + f * 16 + c];
                    orow[f * 16 + c] = v * inv;
                }
            }
        }
    }
}

extern "C" void kernel_launch(void* const* d_in, const int* in_sizes, int n_in,
                              void* d_out, int out_size, void* d_ws, size_t ws_size,
                              hipStream_t stream) {
    const float* x  = (const float*)d_in[0];
    const float* Wq = (const float*)d_in[1];
    const float* bq = (const float*)d_in[2];
    const float* Wk = (const float*)d_in[3];
    const float* bk = (const float*)d_in[4];
    const float* Wv = (const float*)d_in[5];
    const float* bv = (const float*)d_in[6];
    float* outp = (float*)d_out;

    f16*   qf    = (f16*)d_ws;
    f16*   kf    = qf + (size_t)BATCH * SEQ * DQK;
    f16*   vt    = kf + (size_t)BATCH * SEQ * DQK;
    f16*   wt    = vt + (size_t)BATCH * DQK * SEQ;
    float* biasf = (float*)(wt + (size_t)384 * DM);

    wcvt_kernel<<<24, 256, 0, stream>>>(Wq, bq, Wk, bk, Wv, bv, wt, biasf);

    proj_kernel<<<BATCH * SEQ / 64, 512, 0, stream>>>(x, wt, biasf, qf, kf, vt);

    attn_kernel<<<256, 512, 0, stream>>>(qf, kf, vt, outp);
}

// Round 13
// 90.863 us; speedup vs baseline: 1.0902x; 1.0902x over previous
//
#include <hip/hip_runtime.h>
#include <math.h>

#define DM    1024
#define DQK   128
#define BATCH 4
#define SEQ   4096
// 1/sqrt(128) * log2(e) folded into Wq/bq at wcvt time -> softmax uses exp2 directly
#define QSCALE (0.08838834764831845f * 1.4426950408889634f)
#define DEFER_THR 6.0f

typedef _Float16 f16;
typedef _Float16 f16x4 __attribute__((ext_vector_type(4)));
typedef _Float16 f16x8 __attribute__((ext_vector_type(8)));
typedef float    f32x4 __attribute__((ext_vector_type(4)));

__device__ __forceinline__ void stage16(const void* g, unsigned char* l) {
    __builtin_amdgcn_global_load_lds(
        (const __attribute__((address_space(1))) unsigned int*)g,
        (__attribute__((address_space(3))) unsigned int*)l, 16, 0, 0);
}

// ---------------- W convert/transpose pre-kernel: 96 blocks (4x parallelism) ----------------
// grid 96 = 3 sel x 8 k-slabs x 4 n-slabs. Block: [128 k][32 n] tile.
// Coalesced f32 reads -> padded LDS transpose -> coalesced f16x8 writes.
__global__ __launch_bounds__(256) void wcvt_kernel(
    const float* __restrict__ Wq, const float* __restrict__ bq,
    const float* __restrict__ Wk, const float* __restrict__ bk,
    const float* __restrict__ Wv, const float* __restrict__ bv,
    f16* __restrict__ wt, float* __restrict__ biasf)
{
    const int sel   = blockIdx.x >> 5;          // 0..2
    const int rem   = blockIdx.x & 31;
    const int k0    = (rem >> 2) * 128;         // 0..896
    const int n0    = (rem & 3) * 32;           // 0..96
    const float* W; const float* b; float sc;
    if (sel == 0)      { W = Wq; b = bq; sc = QSCALE; }
    else if (sel == 1) { W = Wk; b = bk; sc = 1.0f; }
    else               { W = Wv; b = bv; sc = 1.0f; }

    __shared__ f16 tile[128][40];   // stride 80 B: column reads hit 8 distinct bank groups

    #pragma unroll
    for (int it = 0; it < 16; ++it) {
        int flat = threadIdx.x + it * 256;   // 0..4095
        int kk   = flat >> 5;                 // 0..127
        int cc   = flat & 31;                 // 0..31
        tile[kk][cc] = (f16)(W[(size_t)(k0 + kk) * DQK + n0 + cc] * sc);
    }
    __syncthreads();

    #pragma unroll
    for (int it = 0; it < 2; ++it) {
        int flat  = threadIdx.x + it * 256;   // 0..511
        int nl    = flat >> 4;                 // 0..31
        int kc    = flat & 15;                 // 0..15
        f16x8 v;
        #pragma unroll
        for (int i = 0; i < 8; ++i) v[i] = tile[kc * 8 + i][nl];
        *(f16x8*)(wt + (size_t)(sel * 128 + n0 + nl) * DM + k0 + kc * 8) = v;
    }
    if (rem == 0 && threadIdx.x < 128)
        biasf[sel * 128 + threadIdx.x] = b[threadIdx.x] * sc;
}

// ---------------- Fused QKV projection: W k-slice staged in LDS (round-11 winner) ----------
#define PXOFF 0u        // 2 x 8 KB x double buffer
#define PWOFF 16384u    // 2 x 48 KB W double buffer

__global__ __launch_bounds__(512, 2) void proj_kernel(
    const float* __restrict__ x, const f16* __restrict__ wt,
    const float* __restrict__ biasf,
    f16* __restrict__ qo, f16* __restrict__ ko, f16* __restrict__ vto)
{
    __shared__ __align__(16) unsigned char smem[114688];

    const int tid  = threadIdx.x;
    const int lane = tid & 63;
    const int w    = tid >> 6;
    const int c    = lane & 15;
    const int g    = lane >> 4;
    const int r0   = blockIdx.x * 64;

    // x staging role: thread -> (row, 8-f16 chunk)
    const int srow = tid >> 3;
    const int skq  = tid & 7;
    const float* const xsrc  = x + (size_t)(r0 + srow) * DM + skq * 8;
    const unsigned     swoff = (unsigned)(srow * 128 + ((skq ^ (srow & 7)) * 16));

    // W staging role: per (cc): chunk j = tid + cc*512; n = j>>3, kc = lane&7
    const char* const wtB   = (const char*)wt;
    const unsigned    wsrcsw = (unsigned)(((lane & 7) ^ ((lane >> 3) & 7)) * 16);

    f32x4 acc[4][3];
    #pragma unroll
    for (int rf = 0; rf < 4; ++rf)
        #pragma unroll
        for (int nf = 0; nf < 3; ++nf) acc[rf][nf] = (f32x4)0.f;

    float4 xa, xb2;
    auto gload = [&](int t) {
        const float* p = xsrc + t * 64;
        xa  = *(const float4*)p;
        xb2 = *(const float4*)(p + 4);
    };
    auto swrite = [&](int buf) {
        f16x8 h;
        h[0] = (f16)xa.x;  h[1] = (f16)xa.y;  h[2] = (f16)xa.z;  h[3] = (f16)xa.w;
        h[4] = (f16)xb2.x; h[5] = (f16)xb2.y; h[6] = (f16)xb2.z; h[7] = (f16)xb2.w;
        *(f16x8*)(smem + PXOFF + (unsigned)buf * 8192u + swoff) = h;
    };
    auto stage_W = [&](int t, int pbuf) {
        unsigned char* wdst = smem + PWOFF + (unsigned)pbuf * 49152u + (unsigned)w * 1024u;
        #pragma unroll
        for (int cc = 0; cc < 6; ++cc) {
            const int j = tid + cc * 512;       // 0..3071
            const int n = j >> 3;               // 0..383
            stage16(wtB + (size_t)n * 2048 + (size_t)t * 128 + wsrcsw, wdst + cc * 8192);
        }
    };

    gload(0); swrite(0);
    gload(1);
    stage_W(0, 0);
    __syncthreads();   // x(0) visible, W(0) drained

    for (int t = 0; t < 16; ++t) {
        const int cur = t & 1;
        if (t < 15) swrite(cur ^ 1);          // x(t+1), loaded last iter
        if (t < 14) gload(t + 2);             // x prefetch 2 ahead
        if (t < 15) stage_W(t + 1, cur ^ 1);  // W(t+1), drains at end-of-iter barrier

        // A-frags from swizzled x LDS: row = rf*16+c, k = ks*32 + g*8
        f16x8 af[4][2];
        #pragma unroll
        for (int rf = 0; rf < 4; ++rf)
            #pragma unroll
            for (int ks = 0; ks < 2; ++ks)
                af[rf][ks] = *(const f16x8*)(smem + PXOFF + (unsigned)cur * 8192u
                    + (unsigned)((rf * 16 + c) * 128)
                    + (unsigned)((((4 * ks + g) ^ (c & 7)) * 16)));

        // B-frags from swizzled W LDS: n = w*48 + nf*16 + c, kc = ks*4 + g
        unsigned char* const wbase = smem + PWOFF + (unsigned)cur * 49152u;
        #pragma unroll
        for (int nf = 0; nf < 3; ++nf) {
            #pragma unroll
            for (int ks = 0; ks < 2; ++ks) {
                f16x8 bf = *(const f16x8*)(wbase
                    + (unsigned)((w * 48 + nf * 16 + c) * 128)
                    + (unsigned)((((4 * ks + g) ^ (c & 7)) * 16)));
                #pragma unroll
                for (int rf = 0; rf < 4; ++rf)
                    acc[rf][nf] = __builtin_amdgcn_mfma_f32_16x16x32_f16(
                        af[rf][ks], bf, acc[rf][nf], 0, 0, 0);
            }
        }
        __syncthreads();
    }

    // ---- epilogue: bias + f16, bounce through LDS tile [64][392] for coalesced stores ----
    f16* const tile = (f16*)smem;
    #pragma unroll
    for (int rf = 0; rf < 4; ++rf)
        #pragma unroll
        for (int nf = 0; nf < 3; ++nf) {
            const int n  = w * 48 + nf * 16 + c;
            const float bb = biasf[n];
            #pragma unroll
            for (int r = 0; r < 4; ++r) {
                const int row = rf * 16 + 4 * g + r;
                tile[row * 392 + n] = (f16)(acc[rf][nf][r] + bb);
            }
        }
    __syncthreads();

    #pragma unroll
    for (int it = 0; it < 2; ++it) {
        const int u   = tid + it * 512;
        const int row = u >> 4;
        const int c8  = (u & 15) * 8;
        *(f16x8*)(qo + (size_t)(r0 + row) * DQK + c8) = *(const f16x8*)&tile[row * 392 + c8];
        *(f16x8*)(ko + (size_t)(r0 + row) * DQK + c8) = *(const f16x8*)&tile[row * 392 + 128 + c8];
    }
    const int gb = r0 >> 12;
    const int s0 = r0 & (SEQ - 1);
    #pragma unroll
    for (int it = 0; it < 2; ++it) {
        const int u  = tid + it * 512;
        const int d  = u >> 3;
        const int s8 = (u & 7) * 8;
        f16x8 vv;
        #pragma unroll
        for (int i = 0; i < 8; ++i) vv[i] = tile[(s8 + i) * 392 + 256 + d];
        *(f16x8*)(vto + ((size_t)gb * DQK + d) * SEQ + s0 + s8) = vv;
    }
}

// ---------------- Flash attention: EXACT round-4 winner (66 us) ----------------
#define KOFF 0u
#define VOFF 65536u
#define POFF 131072u
#define MOFF 151552u
#define LOFF 152576u

__global__ __launch_bounds__(512, 2) void attn_kernel(
    const f16* __restrict__ qg, const f16* __restrict__ kg,
    const f16* __restrict__ vtg, float* __restrict__ out)
{
    __shared__ __align__(16) unsigned char smem[153600];

    const int tid  = threadIdx.x;
    const int lane = tid & 63;
    const int w    = tid >> 6;      // 0..7
    const int wq   = w >> 2;        // 0..1
    const int wk   = w & 3;         // 0..3
    const int c    = lane & 15;
    const int g    = lane >> 4;     // 0..3

    const int bid = blockIdx.x;
    const int xcd = bid & 7;
    const int bb  = xcd >> 1;
    const int qt  = (bid >> 3) | ((xcd & 1) << 5);
    const int q0  = qt * 64;

    const f16*  qb = qg  + (size_t)bb * SEQ * DQK;
    const char* kB = (const char*)(kg  + (size_t)bb * SEQ * DQK);
    const char* vB = (const char*)(vtg + (size_t)bb * DQK * SEQ);

    // Q frags (B-operand for swapped QK^T): q = 16n + c, k(d) = ks*32 + 8g + i
    f16x8 qf[2][4];
    {
        const f16* qr = qb + (size_t)(q0 + wq * 32) * DQK;
        #pragma unroll
        for (int n = 0; n < 2; ++n)
            #pragma unroll
            for (int ks = 0; ks < 4; ++ks)
                qf[n][ks] = *(const f16x8*)(qr + (n * 16 + c) * DQK + ks * 32 + 8 * g);
    }

    f32x4 o[2][9];   // [n (q-frag)][d-frag 0..7, 8 = ones column = running l]
    #pragma unroll
    for (int n = 0; n < 2; ++n)
        #pragma unroll
        for (int f = 0; f < 9; ++f) o[n][f] = (f32x4)0.f;
    float m_run[2] = {-3e38f, -3e38f};   // S^T domain: q = 16n + c

    f16x8 onesf;
    #pragma unroll
    for (int i = 0; i < 8; ++i) onesf[i] = (f16)1.0f;

    const unsigned wbase = (unsigned)(tid >> 6) * 1024;

    auto stage_tiles = [&](int t, int pbuf) {
        const int kv0 = t * 128;
        unsigned char* kdst = smem + KOFF + (unsigned)pbuf * 32768u + wbase;
        unsigned char* vdst = smem + VOFF + (unsigned)pbuf * 32768u + wbase;
        #pragma unroll
        for (int cc = 0; cc < 4; ++cc) {
            const int j   = tid + cc * 512;
            const int row = j >> 4;
            const int col = j & 15;
            const int sw  = (col ^ (row & 7)) * 16;
            stage16(kB + (size_t)(kv0 + row) * 256 + sw, kdst + cc * 8192);
            stage16(vB + (size_t)row * 8192 + (size_t)kv0 * 2 + sw, vdst + cc * 8192);
        }
    };

    stage_tiles(0, 0);
    __syncthreads();

    unsigned char* const pmine = smem + POFF + (unsigned)w * 2560u;

    for (int t = 0; t < 32; ++t) {
        const int pb = t & 1;
        if (t < 31) stage_tiles(t + 1, pb ^ 1);

        unsigned char* const kbase = smem + KOFF + (unsigned)pb * 32768u;
        unsigned char* const vbase = smem + VOFF + (unsigned)pb * 32768u;

        // ---- swapped QK^T: S^T[kv 32][q 32] per wave ----
        f32x4 s[2][2];   // [m (kv16)][n (q16)]
        s[0][0] = (f32x4)0.f; s[0][1] = (f32x4)0.f;
        s[1][0] = (f32x4)0.f; s[1][1] = (f32x4)0.f;
        __builtin_amdgcn_s_setprio(1);
        #pragma unroll
        for (int ks = 0; ks < 4; ++ks) {
            #pragma unroll
            for (int m = 0; m < 2; ++m) {
                f16x8 kf = *(const f16x8*)(kbase
                    + (unsigned)(wk * 32 + m * 16 + c) * 256u
                    + (unsigned)(((4 * ks + g) ^ (c & 7)) * 16));
                s[m][0] = __builtin_amdgcn_mfma_f32_16x16x32_f16(kf, qf[0][ks], s[m][0], 0, 0, 0);
                s[m][1] = __builtin_amdgcn_mfma_f32_16x16x32_f16(kf, qf[1][ks], s[m][1], 0, 0, 0);
            }
        }
        __builtin_amdgcn_s_setprio(0);

        // ---- lane-local softmax max (per q-row = 16n + c) ----
        float mt[2];
        #pragma unroll
        for (int n = 0; n < 2; ++n) {
            float a0 = fmaxf(fmaxf(s[0][n][0], s[0][n][1]), fmaxf(s[0][n][2], s[0][n][3]));
            float a1 = fmaxf(fmaxf(s[1][n][0], s[1][n][1]), fmaxf(s[1][n][2], s[1][n][3]));
            float v  = fmaxf(a0, a1);
            v = fmaxf(v, __shfl_xor(v, 16, 64));
            v = fmaxf(v, __shfl_xor(v, 32, 64));
            mt[n] = v;
        }

        // ---- defer-max: rescale only when the running max grows past THR ----
        bool need = (mt[0] > m_run[0] + DEFER_THR) || (mt[1] > m_run[1] + DEFER_THR);
        if (__any(need)) {
            float al[2];
            #pragma unroll
            for (int n = 0; n < 2; ++n) {
                float mn = fmaxf(m_run[n], mt[n]);
                al[n] = __builtin_amdgcn_exp2f(m_run[n] - mn);
                m_run[n] = mn;
            }
            float alo[2][4];
            #pragma unroll
            for (int n = 0; n < 2; ++n)
                #pragma unroll
                for (int r = 0; r < 4; ++r)
                    alo[n][r] = __shfl(al[n], 4 * g + r, 16);
            #pragma unroll
            for (int n = 0; n < 2; ++n)
                #pragma unroll
                for (int f = 0; f < 9; ++f)
                    #pragma unroll
                    for (int r = 0; r < 4; ++r) o[n][f][r] *= alo[n][r];
        }

        // ---- P = exp2(S^T - m), packed b64 stores: P[q = 16n+c][kv = 16m+4g .. +3] ----
        #pragma unroll
        for (int n = 0; n < 2; ++n)
            #pragma unroll
            for (int m = 0; m < 2; ++m) {
                f16x4 h;
                #pragma unroll
                for (int r = 0; r < 4; ++r)
                    h[r] = (f16)__builtin_amdgcn_exp2f(s[m][n][r] - m_run[n]);
                *(f16x4*)(pmine + (unsigned)(16 * n + c) * 80u + (unsigned)(32 * m + 8 * g)) = h;
            }

        // ---- PV: O[32 q][128 d] += P[32 q][32 kv] * V[32 kv][128 d] ----
        f16x8 pa[2];
        pa[0] = *(const f16x8*)(pmine + (unsigned)(c) * 80u + 16u * g);
        pa[1] = *(const f16x8*)(pmine + (unsigned)(16 + c) * 80u + 16u * g);
        __builtin_amdgcn_s_setprio(1);
        #pragma unroll
        for (int df = 0; df < 8; ++df) {
            f16x8 vf = *(const f16x8*)(vbase
                + (unsigned)(df * 16 + c) * 256u
                + (unsigned)(((4 * wk + g) ^ (c & 7)) * 16));
            o[0][df] = __builtin_amdgcn_mfma_f32_16x16x32_f16(pa[0], vf, o[0][df], 0, 0, 0);
            o[1][df] = __builtin_amdgcn_mfma_f32_16x16x32_f16(pa[1], vf, o[1][df], 0, 0, 0);
        }
        o[0][8] = __builtin_amdgcn_mfma_f32_16x16x32_f16(pa[0], onesf, o[0][8], 0, 0, 0);
        o[1][8] = __builtin_amdgcn_mfma_f32_16x16x32_f16(pa[1], onesf, o[1][8], 0, 0, 0);
        __builtin_amdgcn_s_setprio(0);

        __syncthreads();
    }

    // ship final m to O domain (q = 16n + 4g + r)
    float m_o[2][4];
    #pragma unroll
    for (int n = 0; n < 2; ++n)
        #pragma unroll
        for (int r = 0; r < 4; ++r)
            m_o[n][r] = __shfl(m_run[n], 4 * g + r, 16);

    // ---- merge the 4 kv-splits (per wq) via LDS ----
    float* const mld  = (float*)(smem + MOFF);
    float* const lld  = (float*)(smem + LOFF);
    float* const olds = (float*)smem;

    if (wk > 0) {
        const int base = (wq * 3 + (wk - 1)) * 32;
        #pragma unroll
        for (int n = 0; n < 2; ++n)
            #pragma unroll
            for (int f = 0; f < 8; ++f)
                #pragma unroll
                for (int r = 0; r < 4; ++r)
                    olds[(size_t)(base + n * 16 + 4 * g + r) * 132 + f * 16 + c] = o[n][f][r];
        if (c == 0) {
            #pragma unroll
            for (int n = 0; n < 2; ++n)
                #pragma unroll
                for (int r = 0; r < 4; ++r) {
                    mld[(wq * 4 + wk) * 32 + n * 16 + 4 * g + r] = m_o[n][r];
                    lld[(wq * 4 + wk) * 32 + n * 16 + 4 * g + r] = o[n][8][r];
                }
        }
    }
    __syncthreads();

    if (wk == 0) {
        #pragma unroll
        for (int n = 0; n < 2; ++n) {
            #pragma unroll
            for (int r = 0; r < 4; ++r) {
                const int rl = n * 16 + 4 * g + r;
                const float m0 = m_o[n][r];
                const float m1 = mld[(wq * 4 + 1) * 32 + rl];
                const float m2 = mld[(wq * 4 + 2) * 32 + rl];
                const float m3 = mld[(wq * 4 + 3) * 32 + rl];
                const float ms = fmaxf(fmaxf(m0, m1), fmaxf(m2, m3));
                const float a0 = __builtin_amdgcn_exp2f(m0 - ms);
                const float a1 = __builtin_amdgcn_exp2f(m1 - ms);
                const float a2 = __builtin_amdgcn_exp2f(m2 - ms);
                const float a3 = __builtin_amdgcn_exp2f(m3 - ms);
                const float ls = a0 * o[n][8][r]
                               + a1 * lld[(wq * 4 + 1) * 32 + rl]
                               + a2 * lld[(wq * 4 + 2) * 32 + rl]
                               + a3 * lld[(wq * 4 + 3) * 32 + rl];
                const float inv = 1.0f / ls;
                float* orow = out + ((size_t)bb * SEQ + q0 + wq * 32 + rl) * DQK;
                #pragma unroll
                for (int f = 0; f < 8; ++f) {
                    float v = a0 * o[n][f][r]
                            + a1 * olds[(size_t)((wq * 3 + 0) * 32 + rl) * 132 + f * 16 + c]
                            + a2 * olds[(size_t)((wq * 3 + 1) * 32 + rl) * 132 + f * 16 + c]
                            + a3 * olds[(size_t)((wq * 3 + 2) * 32 + rl) * 132 + f * 16 + c];
                    orow[f * 16 + c] = v * inv;
                }
            }
        }
    }
}

extern "C" void kernel_launch(void* const* d_in, const int* in_sizes, int n_in,
                              void* d_out, int out_size, void* d_ws, size_t ws_size,
                              hipStream_t stream) {
    const float* x  = (const float*)d_in[0];
    const float* Wq = (const float*)d_in[1];
    const float* bq = (const float*)d_in[2];
    const float* Wk = (const float*)d_in[3];
    const float* bk = (const float*)d_in[4];
    const float* Wv = (const float*)d_in[5];
    const float* bv = (const float*)d_in[6];
    float* outp = (float*)d_out;

    f16*   qf    = (f16*)d_ws;
    f16*   kf    = qf + (size_t)BATCH * SEQ * DQK;
    f16*   vt    = kf + (size_t)BATCH * SEQ * DQK;
    f16*   wt    = vt + (size_t)BATCH * DQK * SEQ;
    float* biasf = (float*)(wt + (size_t)384 * DM);

    wcvt_kernel<<<96, 256, 0, stream>>>(Wq, bq, Wk, bk, Wv, bv, wt, biasf);

    proj_kernel<<<BATCH * SEQ / 64, 512, 0, stream>>>(x, wt, biasf, qf, kf, vt);

    attn_kernel<<<256, 512, 0, stream>>>(qf, kf, vt, outp);
}

// Round 14
// 89.697 us; speedup vs baseline: 1.1044x; 1.0130x over previous
//
#include <hip/hip_runtime.h>
#include <math.h>

#define DM    1024
#define DQK   128
#define BATCH 4
#define SEQ   4096
// 1/sqrt(128) * log2(e) folded into Wq/bq at wcvt time -> softmax uses exp2 directly
#define QSCALE (0.08838834764831845f * 1.4426950408889634f)
#define DEFER_THR 6.0f

typedef _Float16 f16;
typedef _Float16 f16x4 __attribute__((ext_vector_type(4)));
typedef _Float16 f16x8 __attribute__((ext_vector_type(8)));
typedef float    f32x4 __attribute__((ext_vector_type(4)));

__device__ __forceinline__ void stage16(const void* g, unsigned char* l) {
    __builtin_amdgcn_global_load_lds(
        (const __attribute__((address_space(1))) unsigned int*)g,
        (__attribute__((address_space(3))) unsigned int*)l, 16, 0, 0);
}

// ---------------- W convert/transpose pre-kernel: fragment-linear output ----------------
// grid 96 = 3 sel x 8 k-slabs x 4 n-slabs. Block: [128 k][32 n] tile.
// Output layout: frag (NF = N/16, KS = k/32) stored as 1 KB block at (NF*32+KS)*512 f16,
// element (c = N%16, kk = k%32) at c*32 + kk  ->  MFMA B-frag = contiguous 16B/lane,
// 64 lanes cover the 1 KB block exactly (perfectly coalesced global loads in proj).
__global__ __launch_bounds__(256) void wcvt_kernel(
    const float* __restrict__ Wq, const float* __restrict__ bq,
    const float* __restrict__ Wk, const float* __restrict__ bk,
    const float* __restrict__ Wv, const float* __restrict__ bv,
    f16* __restrict__ wt, float* __restrict__ biasf)
{
    const int sel   = blockIdx.x >> 5;          // 0..2
    const int rem   = blockIdx.x & 31;
    const int k0    = (rem >> 2) * 128;         // 0..896
    const int n0    = (rem & 3) * 32;           // 0..96
    const float* W; const float* b; float sc;
    if (sel == 0)      { W = Wq; b = bq; sc = QSCALE; }
    else if (sel == 1) { W = Wk; b = bk; sc = 1.0f; }
    else               { W = Wv; b = bv; sc = 1.0f; }

    __shared__ f16 tile[128][40];   // stride 80 B: column reads hit 8 distinct bank groups

    #pragma unroll
    for (int it = 0; it < 16; ++it) {
        int flat = threadIdx.x + it * 256;   // 0..4095
        int kk   = flat >> 5;                 // 0..127
        int cc   = flat & 31;                 // 0..31
        tile[kk][cc] = (f16)(W[(size_t)(k0 + kk) * DQK + n0 + cc] * sc);
    }
    __syncthreads();

    #pragma unroll
    for (int it = 0; it < 2; ++it) {
        int flat  = threadIdx.x + it * 256;   // 0..511
        int nl    = flat >> 4;                 // 0..31
        int kc    = flat & 15;                 // 0..15
        f16x8 v;
        #pragma unroll
        for (int i = 0; i < 8; ++i) v[i] = tile[kc * 8 + i][nl];
        const int N  = sel * 128 + n0 + nl;
        const int NF = N >> 4;
        const int c2 = N & 15;
        const int KS = (k0 >> 5) + (kc >> 2);
        const int gg = kc & 3;
        *(f16x8*)(wt + (size_t)(NF * 32 + KS) * 512 + c2 * 32 + gg * 8) = v;
    }
    if (rem == 0 && threadIdx.x < 128)
        biasf[sel * 128 + threadIdx.x] = b[threadIdx.x] * sc;
}

// ---------------- Fused QKV projection: frag-linear W direct from L2, 2 blocks/CU --------
// 256 blocks x 512 thr, 2 blocks/CU (50 KB LDS). Block: 64 rows x 384 cols; wave w:
// 64 rows x 48 cols. Per iter t (k-chunk of 64): x [64][64] f16 reg-staged dbuf (r11
// path, XOR-swizzled); W B-frags = coalesced 16B global loads from L2-resident frag-
// linear table, register-prefetched one iter ahead. 1 barrier/iter. No W LDS at all.
__global__ __launch_bounds__(512, 4) void proj_kernel(
    const float* __restrict__ x, const f16* __restrict__ wt2,
    const float* __restrict__ biasf,
    f16* __restrict__ qo, f16* __restrict__ ko, f16* __restrict__ vto)
{
    __shared__ __align__(16) unsigned char smem[50176];   // 2x8KB x-bufs; reused as 64x392 tile

    const int tid  = threadIdx.x;
    const int lane = tid & 63;
    const int w    = tid >> 6;
    const int c    = lane & 15;
    const int g    = lane >> 4;
    const int r0   = blockIdx.x * 64;

    // x staging role: thread -> (row, 8-f16 chunk)
    const int srow = tid >> 3;
    const int skq  = tid & 7;
    const float* const xsrc  = x + (size_t)(r0 + srow) * DM + skq * 8;
    const unsigned     swoff = (unsigned)(srow * 128 + ((skq ^ (srow & 7)) * 16));

    // per-lane W fragment base: frag (w*3+nf, kstep) at +nf*16384 + kstep*512 f16
    const f16* const wl = wt2 + (size_t)(w * 3) * 32 * 512 + c * 32 + g * 8;

    f32x4 acc[4][3];
    #pragma unroll
    for (int rf = 0; rf < 4; ++rf)
        #pragma unroll
        for (int nf = 0; nf < 3; ++nf) acc[rf][nf] = (f32x4)0.f;

    float4 xa, xb2;
    auto gload = [&](int t) {
        const float* p = xsrc + t * 64;
        xa  = *(const float4*)p;
        xb2 = *(const float4*)(p + 4);
    };
    auto swrite = [&](int buf) {
        f16x8 h;
        h[0] = (f16)xa.x;  h[1] = (f16)xa.y;  h[2] = (f16)xa.z;  h[3] = (f16)xa.w;
        h[4] = (f16)xb2.x; h[5] = (f16)xb2.y; h[6] = (f16)xb2.z; h[7] = (f16)xb2.w;
        *(f16x8*)(smem + (unsigned)buf * 8192u + swoff) = h;
    };

    f16x8 bC[6], bN[6];

    gload(0); swrite(0);
    gload(1);
    #pragma unroll
    for (int nf = 0; nf < 3; ++nf)
        #pragma unroll
        for (int ks = 0; ks < 2; ++ks)
            bC[nf * 2 + ks] = *(const f16x8*)(wl + nf * 16384 + ks * 512);
    __syncthreads();   // x(0) visible

    for (int t = 0; t < 16; ++t) {
        const int cur = t & 1;
        if (t < 15) swrite(cur ^ 1);          // x(t+1), loaded last iter
        if (t < 14) gload(t + 2);             // x prefetch 2 ahead
        if (t < 15) {
            #pragma unroll
            for (int nf = 0; nf < 3; ++nf)
                #pragma unroll
                for (int ks = 0; ks < 2; ++ks)
                    bN[nf * 2 + ks] = *(const f16x8*)(wl + nf * 16384
                                                      + ((t + 1) * 2 + ks) * 512);
        }

        // A-frags from swizzled x LDS (rf-scoped to bound register pressure)
        #pragma unroll
        for (int rf = 0; rf < 4; ++rf) {
            f16x8 af0 = *(const f16x8*)(smem + (unsigned)cur * 8192u
                + (unsigned)((rf * 16 + c) * 128)
                + (unsigned)(((g) ^ (c & 7)) * 16));
            f16x8 af1 = *(const f16x8*)(smem + (unsigned)cur * 8192u
                + (unsigned)((rf * 16 + c) * 128)
                + (unsigned)((((4 + g) ^ (c & 7)) * 16)));
            #pragma unroll
            for (int nf = 0; nf < 3; ++nf) {
                acc[rf][nf] = __builtin_amdgcn_mfma_f32_16x16x32_f16(
                    af0, bC[nf * 2 + 0], acc[rf][nf], 0, 0, 0);
                acc[rf][nf] = __builtin_amdgcn_mfma_f32_16x16x32_f16(
                    af1, bC[nf * 2 + 1], acc[rf][nf], 0, 0, 0);
            }
        }

        if (t < 15) {
            #pragma unroll
            for (int j = 0; j < 6; ++j) bC[j] = bN[j];
        }
        __syncthreads();
    }

    // ---- epilogue: bias + f16, bounce through LDS tile [64][392] for coalesced stores ----
    f16* const tile = (f16*)smem;
    #pragma unroll
    for (int rf = 0; rf < 4; ++rf)
        #pragma unroll
        for (int nf = 0; nf < 3; ++nf) {
            const int n  = w * 48 + nf * 16 + c;
            const float bb = biasf[n];
            #pragma unroll
            for (int r = 0; r < 4; ++r) {
                const int row = rf * 16 + 4 * g + r;
                tile[row * 392 + n] = (f16)(acc[rf][nf][r] + bb);
            }
        }
    __syncthreads();

    #pragma unroll
    for (int it = 0; it < 2; ++it) {
        const int u   = tid + it * 512;
        const int row = u >> 4;
        const int c8  = (u & 15) * 8;
        *(f16x8*)(qo + (size_t)(r0 + row) * DQK + c8) = *(const f16x8*)&tile[row * 392 + c8];
        *(f16x8*)(ko + (size_t)(r0 + row) * DQK + c8) = *(const f16x8*)&tile[row * 392 + 128 + c8];
    }
    const int gb = r0 >> 12;
    const int s0 = r0 & (SEQ - 1);
    #pragma unroll
    for (int it = 0; it < 2; ++it) {
        const int u  = tid + it * 512;
        const int d  = u >> 3;
        const int s8 = (u & 7) * 8;
        f16x8 vv;
        #pragma unroll
        for (int i = 0; i < 8; ++i) vv[i] = tile[(s8 + i) * 392 + 256 + d];
        *(f16x8*)(vto + ((size_t)gb * DQK + d) * SEQ + s0 + s8) = vv;
    }
}

// ---------------- Flash attention: EXACT round-4 winner (66 us) ----------------
#define KOFF 0u
#define VOFF 65536u
#define POFF 131072u
#define MOFF 151552u
#define LOFF 152576u

__global__ __launch_bounds__(512, 2) void attn_kernel(
    const f16* __restrict__ qg, const f16* __restrict__ kg,
    const f16* __restrict__ vtg, float* __restrict__ out)
{
    __shared__ __align__(16) unsigned char smem[153600];

    const int tid  = threadIdx.x;
    const int lane = tid & 63;
    const int w    = tid >> 6;      // 0..7
    const int wq   = w >> 2;        // 0..1
    const int wk   = w & 3;         // 0..3
    const int c    = lane & 15;
    const int g    = lane >> 4;     // 0..3

    const int bid = blockIdx.x;
    const int xcd = bid & 7;
    const int bb  = xcd >> 1;
    const int qt  = (bid >> 3) | ((xcd & 1) << 5);
    const int q0  = qt * 64;

    const f16*  qb = qg  + (size_t)bb * SEQ * DQK;
    const char* kB = (const char*)(kg  + (size_t)bb * SEQ * DQK);
    const char* vB = (const char*)(vtg + (size_t)bb * DQK * SEQ);

    // Q frags (B-operand for swapped QK^T): q = 16n + c, k(d) = ks*32 + 8g + i
    f16x8 qf[2][4];
    {
        const f16* qr = qb + (size_t)(q0 + wq * 32) * DQK;
        #pragma unroll
        for (int n = 0; n < 2; ++n)
            #pragma unroll
            for (int ks = 0; ks < 4; ++ks)
                qf[n][ks] = *(const f16x8*)(qr + (n * 16 + c) * DQK + ks * 32 + 8 * g);
    }

    f32x4 o[2][9];   // [n (q-frag)][d-frag 0..7, 8 = ones column = running l]
    #pragma unroll
    for (int n = 0; n < 2; ++n)
        #pragma unroll
        for (int f = 0; f < 9; ++f) o[n][f] = (f32x4)0.f;
    float m_run[2] = {-3e38f, -3e38f};   // S^T domain: q = 16n + c

    f16x8 onesf;
    #pragma unroll
    for (int i = 0; i < 8; ++i) onesf[i] = (f16)1.0f;

    const unsigned wbase = (unsigned)(tid >> 6) * 1024;

    auto stage_tiles = [&](int t, int pbuf) {
        const int kv0 = t * 128;
        unsigned char* kdst = smem + KOFF + (unsigned)pbuf * 32768u + wbase;
        unsigned char* vdst = smem + VOFF + (unsigned)pbuf * 32768u + wbase;
        #pragma unroll
        for (int cc = 0; cc < 4; ++cc) {
            const int j   = tid + cc * 512;
            const int row = j >> 4;
            const int col = j & 15;
            const int sw  = (col ^ (row & 7)) * 16;
            stage16(kB + (size_t)(kv0 + row) * 256 + sw, kdst + cc * 8192);
            stage16(vB + (size_t)row * 8192 + (size_t)kv0 * 2 + sw, vdst + cc * 8192);
        }
    };

    stage_tiles(0, 0);
    __syncthreads();

    unsigned char* const pmine = smem + POFF + (unsigned)w * 2560u;

    for (int t = 0; t < 32; ++t) {
        const int pb = t & 1;
        if (t < 31) stage_tiles(t + 1, pb ^ 1);

        unsigned char* const kbase = smem + KOFF + (unsigned)pb * 32768u;
        unsigned char* const vbase = smem + VOFF + (unsigned)pb * 32768u;

        // ---- swapped QK^T: S^T[kv 32][q 32] per wave ----
        f32x4 s[2][2];   // [m (kv16)][n (q16)]
        s[0][0] = (f32x4)0.f; s[0][1] = (f32x4)0.f;
        s[1][0] = (f32x4)0.f; s[1][1] = (f32x4)0.f;
        __builtin_amdgcn_s_setprio(1);
        #pragma unroll
        for (int ks = 0; ks < 4; ++ks) {
            #pragma unroll
            for (int m = 0; m < 2; ++m) {
                f16x8 kf = *(const f16x8*)(kbase
                    + (unsigned)(wk * 32 + m * 16 + c) * 256u
                    + (unsigned)(((4 * ks + g) ^ (c & 7)) * 16));
                s[m][0] = __builtin_amdgcn_mfma_f32_16x16x32_f16(kf, qf[0][ks], s[m][0], 0, 0, 0);
                s[m][1] = __builtin_amdgcn_mfma_f32_16x16x32_f16(kf, qf[1][ks], s[m][1], 0, 0, 0);
            }
        }
        __builtin_amdgcn_s_setprio(0);

        // ---- lane-local softmax max (per q-row = 16n + c) ----
        float mt[2];
        #pragma unroll
        for (int n = 0; n < 2; ++n) {
            float a0 = fmaxf(fmaxf(s[0][n][0], s[0][n][1]), fmaxf(s[0][n][2], s[0][n][3]));
            float a1 = fmaxf(fmaxf(s[1][n][0], s[1][n][1]), fmaxf(s[1][n][2], s[1][n][3]));
            float v  = fmaxf(a0, a1);
            v = fmaxf(v, __shfl_xor(v, 16, 64));
            v = fmaxf(v, __shfl_xor(v, 32, 64));
            mt[n] = v;
        }

        // ---- defer-max: rescale only when the running max grows past THR ----
        bool need = (mt[0] > m_run[0] + DEFER_THR) || (mt[1] > m_run[1] + DEFER_THR);
        if (__any(need)) {
            float al[2];
            #pragma unroll
            for (int n = 0; n < 2; ++n) {
                float mn = fmaxf(m_run[n], mt[n]);
                al[n] = __builtin_amdgcn_exp2f(m_run[n] - mn);
                m_run[n] = mn;
            }
            float alo[2][4];
            #pragma unroll
            for (int n = 0; n < 2; ++n)
                #pragma unroll
                for (int r = 0; r < 4; ++r)
                    alo[n][r] = __shfl(al[n], 4 * g + r, 16);
            #pragma unroll
            for (int n = 0; n < 2; ++n)
                #pragma unroll
                for (int f = 0; f < 9; ++f)
                    #pragma unroll
                    for (int r = 0; r < 4; ++r) o[n][f][r] *= alo[n][r];
        }

        // ---- P = exp2(S^T - m), packed b64 stores: P[q = 16n+c][kv = 16m+4g .. +3] ----
        #pragma unroll
        for (int n = 0; n < 2; ++n)
            #pragma unroll
            for (int m = 0; m < 2; ++m) {
                f16x4 h;
                #pragma unroll
                for (int r = 0; r < 4; ++r)
                    h[r] = (f16)__builtin_amdgcn_exp2f(s[m][n][r] - m_run[n]);
                *(f16x4*)(pmine + (unsigned)(16 * n + c) * 80u + (unsigned)(32 * m + 8 * g)) = h;
            }

        // ---- PV: O[32 q][128 d] += P[32 q][32 kv] * V[32 kv][128 d] ----
        f16x8 pa[2];
        pa[0] = *(const f16x8*)(pmine + (unsigned)(c) * 80u + 16u * g);
        pa[1] = *(const f16x8*)(pmine + (unsigned)(16 + c) * 80u + 16u * g);
        __builtin_amdgcn_s_setprio(1);
        #pragma unroll
        for (int df = 0; df < 8; ++df) {
            f16x8 vf = *(const f16x8*)(vbase
                + (unsigned)(df * 16 + c) * 256u
                + (unsigned)(((4 * wk + g) ^ (c & 7)) * 16));
            o[0][df] = __builtin_amdgcn_mfma_f32_16x16x32_f16(pa[0], vf, o[0][df], 0, 0, 0);
            o[1][df] = __builtin_amdgcn_mfma_f32_16x16x32_f16(pa[1], vf, o[1][df], 0, 0, 0);
        }
        o[0][8] = __builtin_amdgcn_mfma_f32_16x16x32_f16(pa[0], onesf, o[0][8], 0, 0, 0);
        o[1][8] = __builtin_amdgcn_mfma_f32_16x16x32_f16(pa[1], onesf, o[1][8], 0, 0, 0);
        __builtin_amdgcn_s_setprio(0);

        __syncthreads();
    }

    // ship final m to O domain (q = 16n + 4g + r)
    float m_o[2][4];
    #pragma unroll
    for (int n = 0; n < 2; ++n)
        #pragma unroll
        for (int r = 0; r < 4; ++r)
            m_o[n][r] = __shfl(m_run[n], 4 * g + r, 16);

    // ---- merge the 4 kv-splits (per wq) via LDS ----
    float* const mld  = (float*)(smem + MOFF);
    float* const lld  = (float*)(smem + LOFF);
    float* const olds = (float*)smem;

    if (wk > 0) {
        const int base = (wq * 3 + (wk - 1)) * 32;
        #pragma unroll
        for (int n = 0; n < 2; ++n)
            #pragma unroll
            for (int f = 0; f < 8; ++f)
                #pragma unroll
                for (int r = 0; r < 4; ++r)
                    olds[(size_t)(base + n * 16 + 4 * g + r) * 132 + f * 16 + c] = o[n][f][r];
        if (c == 0) {
            #pragma unroll
            for (int n = 0; n < 2; ++n)
                #pragma unroll
                for (int r = 0; r < 4; ++r) {
                    mld[(wq * 4 + wk) * 32 + n * 16 + 4 * g + r] = m_o[n][r];
                    lld[(wq * 4 + wk) * 32 + n * 16 + 4 * g + r] = o[n][8][r];
                }
        }
    }
    __syncthreads();

    if (wk == 0) {
        #pragma unroll
        for (int n = 0; n < 2; ++n) {
            #pragma unroll
            for (int r = 0; r < 4; ++r) {
                const int rl = n * 16 + 4 * g + r;
                const float m0 = m_o[n][r];
                const float m1 = mld[(wq * 4 + 1) * 32 + rl];
                const float m2 = mld[(wq * 4 + 2) * 32 + rl];
                const float m3 = mld[(wq * 4 + 3) * 32 + rl];
                const float ms = fmaxf(fmaxf(m0, m1), fmaxf(m2, m3));
                const float a0 = __builtin_amdgcn_exp2f(m0 - ms);
                const float a1 = __builtin_amdgcn_exp2f(m1 - ms);
                const float a2 = __builtin_amdgcn_exp2f(m2 - ms);
                const float a3 = __builtin_amdgcn_exp2f(m3 - ms);
                const float ls = a0 * o[n][8][r]
                               + a1 * lld[(wq * 4 + 1) * 32 + rl]
                               + a2 * lld[(wq * 4 + 2) * 32 + rl]
                               + a3 * lld[(wq * 4 + 3) * 32 + rl];
                const float inv = 1.0f / ls;
                float* orow = out + ((size_t)bb * SEQ + q0 + wq * 32 + rl) * DQK;
                #pragma unroll
                for (int f = 0; f < 8; ++f) {
                    float v = a0 * o[n][f][r]
                            + a1 * olds[(size_t)((wq * 3 + 0) * 32 + rl) * 132 + f * 16 + c]
                            + a2 * olds[(size_t)((wq * 3 + 1) * 32 + rl) * 132 + f * 16 + c]
                            + a3 * olds[(size_t)((wq * 3 + 2) * 32 + rl) * 132 + f * 16 + c];
                    orow[f * 16 + c] = v * inv;
                }
            }
        }
    }
}

extern "C" void kernel_launch(void* const* d_in, const int* in_sizes, int n_in,
                              void* d_out, int out_size, void* d_ws, size_t ws_size,
                              hipStream_t stream) {
    const float* x  = (const float*)d_in[0];
    const float* Wq = (const float*)d_in[1];
    const float* bq = (const float*)d_in[2];
    const float* Wk = (const float*)d_in[3];
    const float* bk = (const float*)d_in[4];
    const float* Wv = (const float*)d_in[5];
    const float* bv = (const float*)d_in[6];
    float* outp = (float*)d_out;

    f16*   qf    = (f16*)d_ws;
    f16*   kf    = qf + (size_t)BATCH * SEQ * DQK;
    f16*   vt    = kf + (size_t)BATCH * SEQ * DQK;
    f16*   wt    = vt + (size_t)BATCH * DQK * SEQ;
    float* biasf = (float*)(wt + (size_t)384 * DM);

    wcvt_kernel<<<96, 256, 0, stream>>>(Wq, bq, Wk, bk, Wv, bv, wt, biasf);

    proj_kernel<<<BATCH * SEQ / 64, 512, 0, stream>>>(x, wt, biasf, qf, kf, vt);

    attn_kernel<<<256, 512, 0, stream>>>(qf, kf, vt, outp);
}

// Round 15
// 89.175 us; speedup vs baseline: 1.1108x; 1.0059x over previous
//
#include <hip/hip_runtime.h>
#include <math.h>

#define DM    1024
#define DQK   128
#define BATCH 4
#define SEQ   4096
// 1/sqrt(128) * log2(e) folded into Wq/bq at wcvt time -> softmax uses exp2 directly
#define QSCALE (0.08838834764831845f * 1.4426950408889634f)
#define DEFER_THR 6.0f

typedef _Float16 f16;
typedef _Float16 f16x4 __attribute__((ext_vector_type(4)));
typedef _Float16 f16x8 __attribute__((ext_vector_type(8)));
typedef float    f32x4 __attribute__((ext_vector_type(4)));

__device__ __forceinline__ void stage16(const void* g, unsigned char* l) {
    __builtin_amdgcn_global_load_lds(
        (const __attribute__((address_space(1))) unsigned int*)g,
        (__attribute__((address_space(3))) unsigned int*)l, 16, 0, 0);
}

// ---------------- W convert/transpose pre-kernel: fragment-linear output ----------------
// grid 96 = 3 sel x 8 k-slabs x 4 n-slabs. Block: [128 k][32 n] tile.
// Output layout: frag (NF = N/16, KS = k/32) stored as 1 KB block at (NF*32+KS)*512 f16,
// element (c = N%16, kk = k%32) at c*32 + kk  ->  MFMA B-frag = contiguous 16B/lane,
// 64 lanes cover the 1 KB block exactly (perfectly coalesced global loads in proj).
__global__ __launch_bounds__(256) void wcvt_kernel(
    const float* __restrict__ Wq, const float* __restrict__ bq,
    const float* __restrict__ Wk, const float* __restrict__ bk,
    const float* __restrict__ Wv, const float* __restrict__ bv,
    f16* __restrict__ wt, float* __restrict__ biasf)
{
    const int sel   = blockIdx.x >> 5;          // 0..2
    const int rem   = blockIdx.x & 31;
    const int k0    = (rem >> 2) * 128;         // 0..896
    const int n0    = (rem & 3) * 32;           // 0..96
    const float* W; const float* b; float sc;
    if (sel == 0)      { W = Wq; b = bq; sc = QSCALE; }
    else if (sel == 1) { W = Wk; b = bk; sc = 1.0f; }
    else               { W = Wv; b = bv; sc = 1.0f; }

    __shared__ f16 tile[128][40];   // stride 80 B: column reads hit 8 distinct bank groups

    #pragma unroll
    for (int it = 0; it < 16; ++it) {
        int flat = threadIdx.x + it * 256;   // 0..4095
        int kk   = flat >> 5;                 // 0..127
        int cc   = flat & 31;                 // 0..31
        tile[kk][cc] = (f16)(W[(size_t)(k0 + kk) * DQK + n0 + cc] * sc);
    }
    __syncthreads();

    #pragma unroll
    for (int it = 0; it < 2; ++it) {
        int flat  = threadIdx.x + it * 256;   // 0..511
        int nl    = flat >> 4;                 // 0..31
        int kc    = flat & 15;                 // 0..15
        f16x8 v;
        #pragma unroll
        for (int i = 0; i < 8; ++i) v[i] = tile[kc * 8 + i][nl];
        const int N  = sel * 128 + n0 + nl;
        const int NF = N >> 4;
        const int c2 = N & 15;
        const int KS = (k0 >> 5) + (kc >> 2);
        const int gg = kc & 3;
        *(f16x8*)(wt + (size_t)(NF * 32 + KS) * 512 + c2 * 32 + gg * 8) = v;
    }
    if (rem == 0 && threadIdx.x < 128)
        biasf[sel * 128 + threadIdx.x] = b[threadIdx.x] * sc;
}

// ---------------- Fused QKV projection: frag-linear W direct from L2 ----------------
// 256 blocks x 512 thr. Block: 64 rows x 384 cols; wave w: 64 rows x 48 cols.
// Per iter t (k-chunk of 64): x [64][64] f16 reg-staged dbuf (XOR-swizzled); W B-frags =
// coalesced 16B global loads from L2-resident frag-linear table, register-prefetched one
// iter ahead with STATIC bA/bB ping-pong (no register copies). 1 barrier/iter. No W LDS.
__global__ __launch_bounds__(512, 4) void proj_kernel(
    const float* __restrict__ x, const f16* __restrict__ wt2,
    const float* __restrict__ biasf,
    f16* __restrict__ qo, f16* __restrict__ ko, f16* __restrict__ vto)
{
    __shared__ __align__(16) unsigned char smem[50176];   // 2x8KB x-bufs; reused as 64x392 tile

    const int tid  = threadIdx.x;
    const int lane = tid & 63;
    const int w    = tid >> 6;
    const int c    = lane & 15;
    const int g    = lane >> 4;
    const int r0   = blockIdx.x * 64;

    // x staging role: thread -> (row, 8-f16 chunk)
    const int srow = tid >> 3;
    const int skq  = tid & 7;
    const float* const xsrc  = x + (size_t)(r0 + srow) * DM + skq * 8;
    const unsigned     swoff = (unsigned)(srow * 128 + ((skq ^ (srow & 7)) * 16));

    // per-lane W fragment base: frag (w*3+nf, kstep) at +nf*16384 + kstep*512 f16
    const f16* const wl = wt2 + (size_t)(w * 3) * 32 * 512 + c * 32 + g * 8;

    f32x4 acc[4][3];
    #pragma unroll
    for (int rf = 0; rf < 4; ++rf)
        #pragma unroll
        for (int nf = 0; nf < 3; ++nf) acc[rf][nf] = (f32x4)0.f;

    float4 xa, xb2;
    auto gload = [&](int t) {
        const float* p = xsrc + t * 64;
        xa  = *(const float4*)p;
        xb2 = *(const float4*)(p + 4);
    };
    auto swrite = [&](int buf) {
        f16x8 h;
        h[0] = (f16)xa.x;  h[1] = (f16)xa.y;  h[2] = (f16)xa.z;  h[3] = (f16)xa.w;
        h[4] = (f16)xb2.x; h[5] = (f16)xb2.y; h[6] = (f16)xb2.z; h[7] = (f16)xb2.w;
        *(f16x8*)(smem + (unsigned)buf * 8192u + swoff) = h;
    };

    f16x8 bA[6], bB[6];

    gload(0); swrite(0);
    gload(1);
    #pragma unroll
    for (int nf = 0; nf < 3; ++nf)
        #pragma unroll
        for (int ks = 0; ks < 2; ++ks)
            bA[nf * 2 + ks] = *(const f16x8*)(wl + nf * 16384 + ks * 512);
    __syncthreads();   // x(0) visible

#define PROJ_ITER(TT, BUSE, BPRE)                                                         \
    {                                                                                     \
        const int cur = (TT) & 1;                                                         \
        if ((TT) < 15) swrite(cur ^ 1);                                                   \
        if ((TT) < 14) gload((TT) + 2);                                                   \
        if ((TT) < 15) {                                                                  \
            _Pragma("unroll")                                                             \
            for (int nf = 0; nf < 3; ++nf)                                                \
                _Pragma("unroll")                                                         \
                for (int ks = 0; ks < 2; ++ks)                                            \
                    BPRE[nf * 2 + ks] = *(const f16x8*)(wl + nf * 16384                   \
                                                        + (((TT) + 1) * 2 + ks) * 512);  \
        }                                                                                 \
        _Pragma("unroll")                                                                 \
        for (int rf = 0; rf < 4; ++rf) {                                                  \
            f16x8 af0 = *(const f16x8*)(smem + (unsigned)cur * 8192u                      \
                + (unsigned)((rf * 16 + c) * 128)                                         \
                + (unsigned)(((g) ^ (c & 7)) * 16));                                      \
            f16x8 af1 = *(const f16x8*)(smem + (unsigned)cur * 8192u                      \
                + (unsigned)((rf * 16 + c) * 128)                                         \
                + (unsigned)((((4 + g) ^ (c & 7)) * 16)));                                \
            _Pragma("unroll")                                                             \
            for (int nf = 0; nf < 3; ++nf) {                                              \
                acc[rf][nf] = __builtin_amdgcn_mfma_f32_16x16x32_f16(                     \
                    af0, BUSE[nf * 2 + 0], acc[rf][nf], 0, 0, 0);                         \
                acc[rf][nf] = __builtin_amdgcn_mfma_f32_16x16x32_f16(                     \
                    af1, BUSE[nf * 2 + 1], acc[rf][nf], 0, 0, 0);                         \
            }                                                                             \
        }                                                                                 \
        __syncthreads();                                                                  \
    }

    for (int t = 0; t < 16; t += 2) {
        PROJ_ITER(t,     bA, bB);
        PROJ_ITER(t + 1, bB, bA);
    }
#undef PROJ_ITER

    // ---- epilogue: bias + f16, bounce through LDS tile [64][392] for coalesced stores ----
    f16* const tile = (f16*)smem;
    #pragma unroll
    for (int rf = 0; rf < 4; ++rf)
        #pragma unroll
        for (int nf = 0; nf < 3; ++nf) {
            const int n  = w * 48 + nf * 16 + c;
            const float bb = biasf[n];
            #pragma unroll
            for (int r = 0; r < 4; ++r) {
                const int row = rf * 16 + 4 * g + r;
                tile[row * 392 + n] = (f16)(acc[rf][nf][r] + bb);
            }
        }
    __syncthreads();

    #pragma unroll
    for (int it = 0; it < 2; ++it) {
        const int u   = tid + it * 512;
        const int row = u >> 4;
        const int c8  = (u & 15) * 8;
        *(f16x8*)(qo + (size_t)(r0 + row) * DQK + c8) = *(const f16x8*)&tile[row * 392 + c8];
        *(f16x8*)(ko + (size_t)(r0 + row) * DQK + c8) = *(const f16x8*)&tile[row * 392 + 128 + c8];
    }
    const int gb = r0 >> 12;
    const int s0 = r0 & (SEQ - 1);
    #pragma unroll
    for (int it = 0; it < 2; ++it) {
        const int u  = tid + it * 512;
        const int d  = u >> 3;
        const int s8 = (u & 7) * 8;
        f16x8 vv;
        #pragma unroll
        for (int i = 0; i < 8; ++i) vv[i] = tile[(s8 + i) * 392 + 256 + d];
        *(f16x8*)(vto + ((size_t)gb * DQK + d) * SEQ + s0 + s8) = vv;
    }
}

// ---------------- Flash attention: EXACT round-4 winner (66 us) ----------------
#define KOFF 0u
#define VOFF 65536u
#define POFF 131072u
#define MOFF 151552u
#define LOFF 152576u

__global__ __launch_bounds__(512, 2) void attn_kernel(
    const f16* __restrict__ qg, const f16* __restrict__ kg,
    const f16* __restrict__ vtg, float* __restrict__ out)
{
    __shared__ __align__(16) unsigned char smem[153600];

    const int tid  = threadIdx.x;
    const int lane = tid & 63;
    const int w    = tid >> 6;      // 0..7
    const int wq   = w >> 2;        // 0..1
    const int wk   = w & 3;         // 0..3
    const int c    = lane & 15;
    const int g    = lane >> 4;     // 0..3

    const int bid = blockIdx.x;
    const int xcd = bid & 7;
    const int bb  = xcd >> 1;
    const int qt  = (bid >> 3) | ((xcd & 1) << 5);
    const int q0  = qt * 64;

    const f16*  qb = qg  + (size_t)bb * SEQ * DQK;
    const char* kB = (const char*)(kg  + (size_t)bb * SEQ * DQK);
    const char* vB = (const char*)(vtg + (size_t)bb * DQK * SEQ);

    // Q frags (B-operand for swapped QK^T): q = 16n + c, k(d) = ks*32 + 8g + i
    f16x8 qf[2][4];
    {
        const f16* qr = qb + (size_t)(q0 + wq * 32) * DQK;
        #pragma unroll
        for (int n = 0; n < 2; ++n)
            #pragma unroll
            for (int ks = 0; ks < 4; ++ks)
                qf[n][ks] = *(const f16x8*)(qr + (n * 16 + c) * DQK + ks * 32 + 8 * g);
    }

    f32x4 o[2][9];   // [n (q-frag)][d-frag 0..7, 8 = ones column = running l]
    #pragma unroll
    for (int n = 0; n < 2; ++n)
        #pragma unroll
        for (int f = 0; f < 9; ++f) o[n][f] = (f32x4)0.f;
    float m_run[2] = {-3e38f, -3e38f};   // S^T domain: q = 16n + c

    f16x8 onesf;
    #pragma unroll
    for (int i = 0; i < 8; ++i) onesf[i] = (f16)1.0f;

    const unsigned wbase = (unsigned)(tid >> 6) * 1024;

    auto stage_tiles = [&](int t, int pbuf) {
        const int kv0 = t * 128;
        unsigned char* kdst = smem + KOFF + (unsigned)pbuf * 32768u + wbase;
        unsigned char* vdst = smem + VOFF + (unsigned)pbuf * 32768u + wbase;
        #pragma unroll
        for (int cc = 0; cc < 4; ++cc) {
            const int j   = tid + cc * 512;
            const int row = j >> 4;
            const int col = j & 15;
            const int sw  = (col ^ (row & 7)) * 16;
            stage16(kB + (size_t)(kv0 + row) * 256 + sw, kdst + cc * 8192);
            stage16(vB + (size_t)row * 8192 + (size_t)kv0 * 2 + sw, vdst + cc * 8192);
        }
    };

    stage_tiles(0, 0);
    __syncthreads();

    unsigned char* const pmine = smem + POFF + (unsigned)w * 2560u;

    for (int t = 0; t < 32; ++t) {
        const int pb = t & 1;
        if (t < 31) stage_tiles(t + 1, pb ^ 1);

        unsigned char* const kbase = smem + KOFF + (unsigned)pb * 32768u;
        unsigned char* const vbase = smem + VOFF + (unsigned)pb * 32768u;

        // ---- swapped QK^T: S^T[kv 32][q 32] per wave ----
        f32x4 s[2][2];   // [m (kv16)][n (q16)]
        s[0][0] = (f32x4)0.f; s[0][1] = (f32x4)0.f;
        s[1][0] = (f32x4)0.f; s[1][1] = (f32x4)0.f;
        __builtin_amdgcn_s_setprio(1);
        #pragma unroll
        for (int ks = 0; ks < 4; ++ks) {
            #pragma unroll
            for (int m = 0; m < 2; ++m) {
                f16x8 kf = *(const f16x8*)(kbase
                    + (unsigned)(wk * 32 + m * 16 + c) * 256u
                    + (unsigned)(((4 * ks + g) ^ (c & 7)) * 16));
                s[m][0] = __builtin_amdgcn_mfma_f32_16x16x32_f16(kf, qf[0][ks], s[m][0], 0, 0, 0);
                s[m][1] = __builtin_amdgcn_mfma_f32_16x16x32_f16(kf, qf[1][ks], s[m][1], 0, 0, 0);
            }
        }
        __builtin_amdgcn_s_setprio(0);

        // ---- lane-local softmax max (per q-row = 16n + c) ----
        float mt[2];
        #pragma unroll
        for (int n = 0; n < 2; ++n) {
            float a0 = fmaxf(fmaxf(s[0][n][0], s[0][n][1]), fmaxf(s[0][n][2], s[0][n][3]));
            float a1 = fmaxf(fmaxf(s[1][n][0], s[1][n][1]), fmaxf(s[1][n][2], s[1][n][3]));
            float v  = fmaxf(a0, a1);
            v = fmaxf(v, __shfl_xor(v, 16, 64));
            v = fmaxf(v, __shfl_xor(v, 32, 64));
            mt[n] = v;
        }

        // ---- defer-max: rescale only when the running max grows past THR ----
        bool need = (mt[0] > m_run[0] + DEFER_THR) || (mt[1] > m_run[1] + DEFER_THR);
        if (__any(need)) {
            float al[2];
            #pragma unroll
            for (int n = 0; n < 2; ++n) {
                float mn = fmaxf(m_run[n], mt[n]);
                al[n] = __builtin_amdgcn_exp2f(m_run[n] - mn);
                m_run[n] = mn;
            }
            float alo[2][4];
            #pragma unroll
            for (int n = 0; n < 2; ++n)
                #pragma unroll
                for (int r = 0; r < 4; ++r)
                    alo[n][r] = __shfl(al[n], 4 * g + r, 16);
            #pragma unroll
            for (int n = 0; n < 2; ++n)
                #pragma unroll
                for (int f = 0; f < 9; ++f)
                    #pragma unroll
                    for (int r = 0; r < 4; ++r) o[n][f][r] *= alo[n][r];
        }

        // ---- P = exp2(S^T - m), packed b64 stores: P[q = 16n+c][kv = 16m+4g .. +3] ----
        #pragma unroll
        for (int n = 0; n < 2; ++n)
            #pragma unroll
            for (int m = 0; m < 2; ++m) {
                f16x4 h;
                #pragma unroll
                for (int r = 0; r < 4; ++r)
                    h[r] = (f16)__builtin_amdgcn_exp2f(s[m][n][r] - m_run[n]);
                *(f16x4*)(pmine + (unsigned)(16 * n + c) * 80u + (unsigned)(32 * m + 8 * g)) = h;
            }

        // ---- PV: O[32 q][128 d] += P[32 q][32 kv] * V[32 kv][128 d] ----
        f16x8 pa[2];
        pa[0] = *(const f16x8*)(pmine + (unsigned)(c) * 80u + 16u * g);
        pa[1] = *(const f16x8*)(pmine + (unsigned)(16 + c) * 80u + 16u * g);
        __builtin_amdgcn_s_setprio(1);
        #pragma unroll
        for (int df = 0; df < 8; ++df) {
            f16x8 vf = *(const f16x8*)(vbase
                + (unsigned)(df * 16 + c) * 256u
                + (unsigned)(((4 * wk + g) ^ (c & 7)) * 16));
            o[0][df] = __builtin_amdgcn_mfma_f32_16x16x32_f16(pa[0], vf, o[0][df], 0, 0, 0);
            o[1][df] = __builtin_amdgcn_mfma_f32_16x16x32_f16(pa[1], vf, o[1][df], 0, 0, 0);
        }
        o[0][8] = __builtin_amdgcn_mfma_f32_16x16x32_f16(pa[0], onesf, o[0][8], 0, 0, 0);
        o[1][8] = __builtin_amdgcn_mfma_f32_16x16x32_f16(pa[1], onesf, o[1][8], 0, 0, 0);
        __builtin_amdgcn_s_setprio(0);

        __syncthreads();
    }

    // ship final m to O domain (q = 16n + 4g + r)
    float m_o[2][4];
    #pragma unroll
    for (int n = 0; n < 2; ++n)
        #pragma unroll
        for (int r = 0; r < 4; ++r)
            m_o[n][r] = __shfl(m_run[n], 4 * g + r, 16);

    // ---- merge the 4 kv-splits (per wq) via LDS ----
    float* const mld  = (float*)(smem + MOFF);
    float* const lld  = (float*)(smem + LOFF);
    float* const olds = (float*)smem;

    if (wk > 0) {
        const int base = (wq * 3 + (wk - 1)) * 32;
        #pragma unroll
        for (int n = 0; n < 2; ++n)
            #pragma unroll
            for (int f = 0; f < 8; ++f)
                #pragma unroll
                for (int r = 0; r < 4; ++r)
                    olds[(size_t)(base + n * 16 + 4 * g + r) * 132 + f * 16 + c] = o[n][f][r];
        if (c == 0) {
            #pragma unroll
            for (int n = 0; n < 2; ++n)
                #pragma unroll
                for (int r = 0; r < 4; ++r) {
                    mld[(wq * 4 + wk) * 32 + n * 16 + 4 * g + r] = m_o[n][r];
                    lld[(wq * 4 + wk) * 32 + n * 16 + 4 * g + r] = o[n][8][r];
                }
        }
    }
    __syncthreads();

    if (wk == 0) {
        #pragma unroll
        for (int n = 0; n < 2; ++n) {
            #pragma unroll
            for (int r = 0; r < 4; ++r) {
                const int rl = n * 16 + 4 * g + r;
                const float m0 = m_o[n][r];
                const float m1 = mld[(wq * 4 + 1) * 32 + rl];
                const float m2 = mld[(wq * 4 + 2) * 32 + rl];
                const float m3 = mld[(wq * 4 + 3) * 32 + rl];
                const float ms = fmaxf(fmaxf(m0, m1), fmaxf(m2, m3));
                const float a0 = __builtin_amdgcn_exp2f(m0 - ms);
                const float a1 = __builtin_amdgcn_exp2f(m1 - ms);
                const float a2 = __builtin_amdgcn_exp2f(m2 - ms);
                const float a3 = __builtin_amdgcn_exp2f(m3 - ms);
                const float ls = a0 * o[n][8][r]
                               + a1 * lld[(wq * 4 + 1) * 32 + rl]
                               + a2 * lld[(wq * 4 + 2) * 32 + rl]
                               + a3 * lld[(wq * 4 + 3) * 32 + rl];
                const float inv = 1.0f / ls;
                float* orow = out + ((size_t)bb * SEQ + q0 + wq * 32 + rl) * DQK;
                #pragma unroll
                for (int f = 0; f < 8; ++f) {
                    float v = a0 * o[n][f][r]
                            + a1 * olds[(size_t)((wq * 3 + 0) * 32 + rl) * 132 + f * 16 + c]
                            + a2 * olds[(size_t)((wq * 3 + 1) * 32 + rl) * 132 + f * 16 + c]
                            + a3 * olds[(size_t)((wq * 3 + 2) * 32 + rl) * 132 + f * 16 + c];
                    orow[f * 16 + c] = v * inv;
                }
            }
        }
    }
}

extern "C" void kernel_launch(void* const* d_in, const int* in_sizes, int n_in,
                              void* d_out, int out_size, void* d_ws, size_t ws_size,
                              hipStream_t stream) {
    const float* x  = (const float*)d_in[0];
    const float* Wq = (const float*)d_in[1];
    const float* bq = (const float*)d_in[2];
    const float* Wk = (const float*)d_in[3];
    const float* bk = (const float*)d_in[4];
    const float* Wv = (const float*)d_in[5];
    const float* bv = (const float*)d_in[6];
    float* outp = (float*)d_out;

    f16*   qf    = (f16*)d_ws;
    f16*   kf    = qf + (size_t)BATCH * SEQ * DQK;
    f16*   vt    = kf + (size_t)BATCH * SEQ * DQK;
    f16*   wt    = vt + (size_t)BATCH * DQK * SEQ;
    float* biasf = (float*)(wt + (size_t)384 * DM);

    wcvt_kernel<<<96, 256, 0, stream>>>(Wq, bq, Wk, bk, Wv, bv, wt, biasf);

    proj_kernel<<<BATCH * SEQ / 64, 512, 0, stream>>>(x, wt, biasf, qf, kf, vt);

    attn_kernel<<<256, 512, 0, stream>>>(qf, kf, vt, outp);
}